// Round 2
// baseline (42.480 us; speedup 1.0000x reference)
//
#include <hip/hip_runtime.h>

// X,Y: [32,3,512,512] f32 reinterpreted flat as NHWC [32][512][512][3].
// loss = sum_b mean_{crop} [ filt(d^2) - filt(d)^2 ],  d = X - Y,
// filt = separable 3x3 gaussian (sigma=1.5): taps [g0, g1, g0].
// Crop [5:-5] => reflect padding never exercised.

constexpr int Wd     = 512;
constexpr int Hd     = 512;
constexpr int Cd     = 3;
constexpr int ROW    = Hd * Cd;          // 1536 floats per w-row
constexpr int CROPc  = 5;
constexpr int NOUTc  = Wd - 2 * CROPc;   // 502
// hc = h*3+c flat column index. Outputs: hc in [15,1520]. Halo: [12,1523].
constexpr int HC_LO  = 15;
constexpr int HC_HI  = 1520;
constexpr int OUT_PER_WAVE = 58;         // lanes 3..60 produce outputs
constexpr int NHCW   = (NOUTc * Cd + OUT_PER_WAVE - 1) / OUT_PER_WAVE; // 26
constexpr int NCHUNK = 8;
constexpr int CHUNKc = 63;               // 63*7 + 61 = 502
constexpr int BLOCK  = 256;
constexpr int NWAVES = 32 * NCHUNK * NHCW;      // 6656
constexpr int NBLK   = NWAVES / (BLOCK / 64);   // 1664
static_assert(NWAVES % (BLOCK / 64) == 0, "");

__global__ __launch_bounds__(BLOCK) void locvar_kernel(
    const float* __restrict__ X,
    const float* __restrict__ Y,
    float* __restrict__ partial)
{
    const int lane = threadIdx.x & 63;
    const int widx = threadIdx.x >> 6;
    const int gw   = blockIdx.x * (BLOCK / 64) + widx;   // 0..6655

    const int hcw   = gw % NHCW;
    const int rest  = gw / NHCW;
    const int chunk = rest % NCHUNK;
    const int b     = rest / NCHUNK;

    const int hc = 12 + OUT_PER_WAVE * hcw + lane;   // 12..1525 (< 1536, safe)
    const int w0 = CROPc + chunk * CHUNKc;
    const int wn = min(CHUNKc, CROPc + NOUTc - w0);  // 63 or 61

    const bool valid = (lane >= 3) && (lane <= 60) && (hc >= HC_LO) && (hc <= HC_HI);
    const float vmask = valid ? 1.0f : 0.0f;

    // gaussian taps (sigma=1.5, ksize=3); constant-folded at -O3
    const float e  = expf(-1.0f / 4.5f);
    const float g1 = 1.0f / (1.0f + 2.0f * e);
    const float g0 = e * g1;

    // bpermute byte addresses for lane-3 / lane+3 (precomputed once)
    const int am = ((lane - 3) & 63) << 2;
    const int ap = ((lane + 3) & 63) << 2;

    const size_t base = (size_t)b * Wd * ROW + (size_t)hc;

    // Per-row: one load of X,Y each; neighbors via cross-lane bpermute.
#define ROWSUMS(OFF, Rr, Qq)                                                     \
    {                                                                            \
        float dd  = X[(OFF)] - Y[(OFF)];                                         \
        float dmv = __int_as_float(                                              \
            __builtin_amdgcn_ds_bpermute(am, __float_as_int(dd)));               \
        float dpv = __int_as_float(                                              \
            __builtin_amdgcn_ds_bpermute(ap, __float_as_int(dd)));               \
        Rr = g0 * (dmv + dpv) + g1 * dd;                                         \
        Qq = g0 * fmaf(dpv, dpv, dmv * dmv) + g1 * (dd * dd);                    \
    }

    float R0, R1, Q0, Q1;
    {
        size_t off = base + (size_t)(w0 - 1) * ROW;
        ROWSUMS(off, R0, Q0);
        off += ROW;
        ROWSUMS(off, R1, Q1);
    }

    float acc = 0.0f;
    size_t off = base + (size_t)(w0 + 1) * ROW;
    #pragma unroll 2
    for (int i = 0; i < wn; ++i, off += ROW) {
        float R2, Q2;
        ROWSUMS(off, R2, Q2);

        float S1 = g0 * (R0 + R2) + g1 * R1;   // filt(d)
        float S2 = g0 * (Q0 + Q2) + g1 * Q1;   // filt(d^2)
        acc += vmask * fmaf(-S1, S1, S2);

        R0 = R1; R1 = R2;
        Q0 = Q1; Q1 = Q2;
    }
#undef ROWSUMS

    // deterministic reduction: wave shuffle then LDS
    #pragma unroll
    for (int o = 32; o > 0; o >>= 1) acc += __shfl_down(acc, o, 64);

    __shared__ float sdata[BLOCK / 64];
    if (lane == 0) sdata[widx] = acc;
    __syncthreads();
    if (threadIdx.x == 0) {
        float s = 0.0f;
        #pragma unroll
        for (int i = 0; i < BLOCK / 64; ++i) s += sdata[i];
        partial[blockIdx.x] = s;
    }
}

__global__ __launch_bounds__(BLOCK) void reduce_kernel(
    const float* __restrict__ partial,
    float* __restrict__ out)
{
    float acc = 0.0f;
    for (int i = threadIdx.x; i < NBLK; i += BLOCK) acc += partial[i];

    #pragma unroll
    for (int o = 32; o > 0; o >>= 1) acc += __shfl_down(acc, o, 64);

    __shared__ float sdata[BLOCK / 64];
    const int lane = threadIdx.x & 63;
    const int wid  = threadIdx.x >> 6;
    if (lane == 0) sdata[wid] = acc;
    __syncthreads();
    if (threadIdx.x == 0) {
        float s = 0.0f;
        #pragma unroll
        for (int i = 0; i < BLOCK / 64; ++i) s += sdata[i];
        out[0] = s * (1.0f / ((float)NOUTc * (float)NOUTc * (float)Cd));
    }
}

extern "C" void kernel_launch(void* const* d_in, const int* in_sizes, int n_in,
                              void* d_out, int out_size, void* d_ws, size_t ws_size,
                              hipStream_t stream) {
    const float* X = (const float*)d_in[0];
    const float* Y = (const float*)d_in[1];
    float* out     = (float*)d_out;
    float* partial = (float*)d_ws;   // NBLK floats

    locvar_kernel<<<NBLK, BLOCK, 0, stream>>>(X, Y, partial);
    reduce_kernel<<<1, BLOCK, 0, stream>>>(partial, out);
}